// Round 3
// baseline (441.943 us; speedup 1.0000x reference)
//
#include <hip/hip_runtime.h>
#include <hip/hip_bf16.h>

#define B 32
#define H 8
#define T 512
#define S 196
#define D 768
#define K 51
#define LAYER 2

// K1: cosine similarity weights + fm passthrough.
// One 64-lane wave per (b,t) row of target_embed. D=768 floats = 192 float4
// -> 3 float4 per lane. Fused dot, |x|^2, |y|^2, butterfly reduce.
// Blocks 0..24 additionally copy fore_map -> out_fm (B*S = 6272 elements).
__global__ __launch_bounds__(256) void k1_weights(const float* __restrict__ te,
                                                  const float* __restrict__ fr,
                                                  const float* __restrict__ fm,
                                                  float* __restrict__ w,
                                                  float* __restrict__ out_fm) {
    int gtid = blockIdx.x * 256 + threadIdx.x;
    if (gtid < B * S) out_fm[gtid] = fm[gtid];

    int wave = threadIdx.x >> 6, lane = threadIdx.x & 63;
    int row = blockIdx.x * 4 + wave;          // [0, B*T), grid exact
    int b = row >> 9;                          // T = 512
    const float4* a = (const float4*)(te + (size_t)row * D);
    const float4* y = (const float4*)(fr + (size_t)b * D);
    float dot = 0.f, sx = 0.f, sy = 0.f;
#pragma unroll
    for (int i = 0; i < 3; ++i) {
        float4 av = a[lane + 64 * i];
        float4 yv = y[lane + 64 * i];
        dot += av.x * yv.x + av.y * yv.y + av.z * yv.z + av.w * yv.w;
        sx  += av.x * av.x + av.y * av.y + av.z * av.z + av.w * av.w;
        sy  += yv.x * yv.x + yv.y * yv.y + yv.z * yv.z + yv.w * yv.w;
    }
#pragma unroll
    for (int m = 32; m; m >>= 1) {
        dot += __shfl_xor(dot, m);
        sx  += __shfl_xor(sx, m);
        sy  += __shfl_xor(sy, m);
    }
    if (lane == 0)
        w[row] = dot / fmaxf(sqrtf(sx) * sqrtf(sy), 1e-8f);
}

// K2: fused top-k + gather + normalize + max-reduce. One block (4 waves) per batch.
//  1. bitonic sort of 512 packed (value,idx) keys in LDS (descending value,
//     ascending idx on ties — matches lax.top_k).
//  2. each wave processes ranks j = wave, wave+4, ...: gathers the 8-head
//     attention row at t=idx[j], means heads, relu(w*.), wave min/max via
//     butterfly, normalizes, LDS atomicMax into acc[196].
//  3. writes out_ta and out_idx.
__global__ __launch_bounds__(256) void k2_fused(const float* __restrict__ attn2,
                                                const float* __restrict__ w,
                                                float* __restrict__ out_ta,
                                                float* __restrict__ out_idx) {
    __shared__ unsigned long long keys[T];
    __shared__ float wlds[T];
    __shared__ unsigned acc[256];
    int b = blockIdx.x, tid = threadIdx.x;
    acc[tid] = 0u;                            // values >= 0, uint order == float order
    for (int i = tid; i < T; i += 256) {
        float wv = w[b * T + i];
        wlds[i] = wv;
        unsigned u = __float_as_uint(wv);
        u = (u & 0x80000000u) ? ~u : (u | 0x80000000u);  // ascending-uint == ascending-float
        keys[i] = (((unsigned long long)(~u)) << 32) | (unsigned)i;
    }
    for (int k = 2; k <= T; k <<= 1) {
        for (int j = k >> 1; j > 0; j >>= 1) {
            __syncthreads();
            for (int t = tid; t < T; t += 256) {
                int ixj = t ^ j;
                if (ixj > t) {
                    unsigned long long x = keys[t], z = keys[ixj];
                    bool up = ((t & k) == 0);
                    if ((x > z) == up) { keys[t] = z; keys[ixj] = x; }
                }
            }
        }
    }
    __syncthreads();
    if (tid < K)
        out_idx[b * K + tid] = (float)(unsigned)(keys[tid] & 0xFFFFFFFFu);

    int wave = tid >> 6, lane = tid & 63;
    for (int j = wave; j < K; j += 4) {
        int t = (int)(unsigned)(keys[j] & 0xFFFFFFFFu);
        float wt = wlds[t];
        const float* base = attn2 + ((size_t)(b * H) * T + t) * S;
        float a0 = 0.f, a1 = 0.f, a2 = 0.f, a3 = 0.f;
#pragma unroll
        for (int h = 0; h < H; ++h) {
            const float* p = base + (size_t)h * T * S;
            a0 += p[lane];
            a1 += p[lane + 64];
            a2 += p[lane + 128];
            if (lane < S - 192) a3 += p[lane + 192];
        }
        float v0 = fmaxf(wt * a0 * 0.125f, 0.f);
        float v1 = fmaxf(wt * a1 * 0.125f, 0.f);
        float v2 = fmaxf(wt * a2 * 0.125f, 0.f);
        float v3 = fmaxf(wt * a3 * 0.125f, 0.f);   // meaningful only for lane < 4
        float mn = fminf(fminf(v0, v1), v2);
        float mx = fmaxf(fmaxf(v0, v1), v2);
        if (lane < S - 192) { mn = fminf(mn, v3); mx = fmaxf(mx, v3); }
#pragma unroll
        for (int m = 32; m; m >>= 1) {
            mn = fminf(mn, __shfl_xor(mn, m));
            mx = fmaxf(mx, __shfl_xor(mx, m));
        }
        // ref: sub min, then amax = clip(max(after_sub), 1e-12, 1.0)
        float amax = fminf(fmaxf(mx - mn, 1e-12f), 1.0f);
        atomicMax(&acc[lane],       __float_as_uint((v0 - mn) / amax));
        atomicMax(&acc[lane + 64],  __float_as_uint((v1 - mn) / amax));
        atomicMax(&acc[lane + 128], __float_as_uint((v2 - mn) / amax));
        if (lane < S - 192)
            atomicMax(&acc[lane + 192], __float_as_uint((v3 - mn) / amax));
    }
    __syncthreads();
    if (tid < S) out_ta[b * S + tid] = __uint_as_float(acc[tid]);
}

extern "C" void kernel_launch(void* const* d_in, const int* in_sizes, int n_in,
                              void* d_out, int out_size, void* d_ws, size_t ws_size,
                              hipStream_t stream) {
    const float* fore_map = (const float*)d_in[0];   // B*1*S
    const float* fore_rep = (const float*)d_in[1];   // B*D
    const float* target   = (const float*)d_in[2];   // B*T*D
    const float* attns    = (const float*)d_in[3];   // 3*B*H*T*S
    const float* attn2 = attns + (size_t)LAYER * B * H * T * S;

    float* w_buf = (float*)d_ws;              // B*T fp32 weights

    float* out_fm  = (float*)d_out;           // outputs are float32, concat flat
    float* out_ta  = out_fm + B * S;
    float* out_idx = out_ta + B * S;

    k1_weights<<<(B * T) / 4, 256, 0, stream>>>(target, fore_rep, fore_map, w_buf, out_fm);
    k2_fused<<<B, 256, 0, stream>>>(attn2, w_buf, out_ta, out_idx);
}

// Round 4
// 391.369 us; speedup vs baseline: 1.1292x; 1.1292x over previous
//
#include <hip/hip_runtime.h>
#include <hip/hip_bf16.h>

#define B 32
#define H 8
#define T 512
#define S 196
#define D 768
#define K 51
#define LAYER 2

// K1: cosine similarity weights + fm passthrough + zero out_ta.
// One 64-lane wave per (b,t) row of target_embed. D=768 floats = 192 float4
// -> 3 float4 per lane. Fused dot, |x|^2, |y|^2, butterfly reduce.
// First 25 blocks also copy fore_map -> out_fm and zero out_ta (B*S = 6272),
// which k3 then accumulates into with uint atomicMax (stream-ordered, safe).
__global__ __launch_bounds__(256) void k1_weights(const float* __restrict__ te,
                                                  const float* __restrict__ fr,
                                                  const float* __restrict__ fm,
                                                  float* __restrict__ w,
                                                  float* __restrict__ out_fm,
                                                  float* __restrict__ out_ta) {
    int gtid = blockIdx.x * 256 + threadIdx.x;
    if (gtid < B * S) {
        out_fm[gtid] = fm[gtid];
        out_ta[gtid] = 0.0f;
    }

    int wave = threadIdx.x >> 6, lane = threadIdx.x & 63;
    int row = blockIdx.x * 4 + wave;          // [0, B*T), grid exact
    int b = row >> 9;                          // T = 512
    const float4* a = (const float4*)(te + (size_t)row * D);
    const float4* y = (const float4*)(fr + (size_t)b * D);
    float dot = 0.f, sx = 0.f, sy = 0.f;
#pragma unroll
    for (int i = 0; i < 3; ++i) {
        float4 av = a[lane + 64 * i];
        float4 yv = y[lane + 64 * i];
        dot += av.x * yv.x + av.y * yv.y + av.z * yv.z + av.w * yv.w;
        sx  += av.x * av.x + av.y * av.y + av.z * av.z + av.w * av.w;
        sy  += yv.x * yv.x + yv.y * yv.y + yv.z * yv.z + yv.w * yv.w;
    }
#pragma unroll
    for (int m = 32; m; m >>= 1) {
        dot += __shfl_xor(dot, m);
        sx  += __shfl_xor(sx, m);
        sy  += __shfl_xor(sy, m);
    }
    if (lane == 0)
        w[row] = dot / fmaxf(sqrtf(sx) * sqrtf(sy), 1e-8f);
}

// K2: per-batch top-51 via full bitonic sort of 512 packed keys in LDS.
// Key (sorted ascending) = (~mapped_float << 32) | idx  => descending value,
// ascending index on ties — matches lax.top_k.
__global__ __launch_bounds__(256) void k2_topk(const float* __restrict__ w,
                                               int* __restrict__ idx_ws,
                                               float* __restrict__ out_idx) {
    __shared__ unsigned long long keys[T];
    int b = blockIdx.x, tid = threadIdx.x;
    for (int i = tid; i < T; i += 256) {
        unsigned u = __float_as_uint(w[b * T + i]);
        u = (u & 0x80000000u) ? ~u : (u | 0x80000000u);  // ascending-uint == ascending-float
        keys[i] = (((unsigned long long)(~u)) << 32) | (unsigned)i;
    }
    for (int k = 2; k <= T; k <<= 1) {
        for (int j = k >> 1; j > 0; j >>= 1) {
            __syncthreads();
            for (int t = tid; t < T; t += 256) {
                int ixj = t ^ j;
                if (ixj > t) {
                    unsigned long long x = keys[t], z = keys[ixj];
                    bool up = ((t & k) == 0);
                    if ((x > z) == up) { keys[t] = z; keys[ixj] = x; }
                }
            }
        }
    }
    __syncthreads();
    if (tid < K) {
        int id = (int)(unsigned)(keys[tid] & 0xFFFFFFFFu);
        idx_ws[b * K + tid] = id;
        out_idx[b * K + tid] = (float)id;
    }
}

// K3: one wave per (b, rank) — 1632 waves across 408 blocks for latency hiding.
// Gather the 8-head attention row for t=idx[b][j], mean over heads, relu(w*.),
// wave min/max via butterfly, normalize, global uint-atomicMax into out_ta
// (values >= 0, buffer pre-zeroed by k1; uint order == float order on [0,inf)).
__global__ __launch_bounds__(256) void k3_rows(const float* __restrict__ attn2,
                                               const float* __restrict__ w,
                                               const int* __restrict__ idx_ws,
                                               float* __restrict__ out_ta) {
    int wave = threadIdx.x >> 6, lane = threadIdx.x & 63;
    int flat = blockIdx.x * 4 + wave;
    if (flat >= B * K) return;
    int b = flat / K, j = flat % K;
    int t = idx_ws[b * K + j];
    float wt = w[b * T + t];
    const float* base = attn2 + ((size_t)(b * H) * T + t) * S;
    float a0 = 0.f, a1 = 0.f, a2 = 0.f, a3 = 0.f;
#pragma unroll
    for (int h = 0; h < H; ++h) {
        const float* p = base + (size_t)h * T * S;
        a0 += p[lane];
        a1 += p[lane + 64];
        a2 += p[lane + 128];
        if (lane < S - 192) a3 += p[lane + 192];
    }
    float v0 = fmaxf(wt * a0 * 0.125f, 0.f);
    float v1 = fmaxf(wt * a1 * 0.125f, 0.f);
    float v2 = fmaxf(wt * a2 * 0.125f, 0.f);
    float v3 = fmaxf(wt * a3 * 0.125f, 0.f);   // meaningful only for lane < 4
    float mn = fminf(fminf(v0, v1), v2);
    float mx = fmaxf(fmaxf(v0, v1), v2);
    if (lane < S - 192) { mn = fminf(mn, v3); mx = fmaxf(mx, v3); }
#pragma unroll
    for (int m = 32; m; m >>= 1) {
        mn = fminf(mn, __shfl_xor(mn, m));
        mx = fmaxf(mx, __shfl_xor(mx, m));
    }
    // ref: sub min, then amax = clip(max(after_sub), 1e-12, 1.0)
    float amax = fminf(fmaxf(mx - mn, 1e-12f), 1.0f);
    unsigned* tp = (unsigned*)(out_ta + b * S);
    atomicMax(tp + lane,        __float_as_uint((v0 - mn) / amax));
    atomicMax(tp + lane + 64,   __float_as_uint((v1 - mn) / amax));
    atomicMax(tp + lane + 128,  __float_as_uint((v2 - mn) / amax));
    if (lane < S - 192)
        atomicMax(tp + lane + 192, __float_as_uint((v3 - mn) / amax));
}

extern "C" void kernel_launch(void* const* d_in, const int* in_sizes, int n_in,
                              void* d_out, int out_size, void* d_ws, size_t ws_size,
                              hipStream_t stream) {
    const float* fore_map = (const float*)d_in[0];   // B*1*S
    const float* fore_rep = (const float*)d_in[1];   // B*D
    const float* target   = (const float*)d_in[2];   // B*T*D
    const float* attns    = (const float*)d_in[3];   // 3*B*H*T*S
    const float* attn2 = attns + (size_t)LAYER * B * H * T * S;

    float* w_buf = (float*)d_ws;                 // B*T fp32 weights
    int* idx_ws  = (int*)(w_buf + B * T);        // B*K int32

    float* out_fm  = (float*)d_out;              // outputs are float32, concat flat
    float* out_ta  = out_fm + B * S;
    float* out_idx = out_ta + B * S;

    k1_weights<<<(B * T) / 4, 256, 0, stream>>>(target, fore_rep, fore_map,
                                                w_buf, out_fm, out_ta);
    k2_topk<<<B, 256, 0, stream>>>(w_buf, idx_ws, out_idx);
    k3_rows<<<(B * K + 3) / 4, 256, 0, stream>>>(attn2, w_buf, idx_ws, out_ta);
}